// Round 28
// baseline (109.901 us; speedup 1.0000x reference)
//
#include <hip/hip_runtime.h>
#include <hip/hip_bf16.h>
#include <hip/hip_fp16.h>

// N = 100000 nodes, D = 64 features, E = 1250000 edges.
// Inputs: old_g[N,D] f32, W[D,D] f32, edge_weight[E,1] f32,
//         history_db[N,D] f32, src[E] i32, dst[E] i32
// Output: concat(nodes_new[N,D], history_new[N,D]) f32.
//
// Pipeline (3 dispatches + 1 tiny memset):
//  (0) memset bcur[256] = 0;
//  (1) fused gemm||bucketA (mixed-block): GEMM fp16-out || LDS counting-
//      sort into padded bucket regions (dense writes);
//  (2) bucketB: per-bucket LDS per-node hist + scan -> nodeinfo{beg,deg},
//      exact-CSR scatter into the bucket's srcw window;
//  (3) node kernel: ALL streaming accesses non-temporal (nodeinfo, srcw,
//      old_g, hist, both outputs) so the 12.8MB h16 gather table stays
//      L2-resident (R27: 38MB gather re-fetch vs 12.8MB table = stream
//      eviction).  Gathers stay cached.

#define D_FEAT 64
#define WQ_SCALE 32767.0f
#define WQ_INV   (1.0f / 32767.0f)
#define BSHIFT 9          // 512 nodes per bucket
#define BN     (1 << BSHIFT)
#define NBUCK_MAX 256     // ceil(100000/512)=196
#define BCAP   8192       // per-bucket region capacity (mean 6400 + 22 sigma)
#define PA_BLOCKS 512
#define PA_CHUNK_MAX 2560 // >= ceil(E/PA_BLOCKS)=2442

#define GR 128
#define GPAD 66
#define SMEM_BYTES 50176

typedef int   v4i __attribute__((ext_vector_type(4)));
typedef int   v2i __attribute__((ext_vector_type(2)));
typedef float v4f __attribute__((ext_vector_type(4)));

__device__ __forceinline__ v4f nt_load4f(const float* p) {
    return __builtin_nontemporal_load(reinterpret_cast<const v4f*>(p));
}

__device__ __forceinline__ unsigned pack_edge(int s, float w) {
    int wq = __float2int_rn(w * WQ_SCALE);
    wq = min(wq, 32767);
    wq = max(wq, 0);
    return (unsigned)s | ((unsigned)wq << 17);
}

// ---------------------------------------------------------------------------
// K1: fused gemm || bucketA.
// ---------------------------------------------------------------------------
__global__ __launch_bounds__(256) void gemm_bucketA_kernel(
    const float* __restrict__ g, const float* __restrict__ W,
    __half* __restrict__ h16, int N,
    const int* __restrict__ src, const int* __restrict__ dst,
    const float* __restrict__ ew, int* __restrict__ bcur,
    int2* __restrict__ staged, int E, int chunk, int nbuck, int gemmGrid) {
    __shared__ __align__(16) char smem[SMEM_BYTES];
    const int tid = threadIdx.x;

    if (blockIdx.x < gemmGrid) {
        // ----- GEMM phase -----
        float* Wl = reinterpret_cast<float*>(smem);
        float (*Gl)[GPAD] = reinterpret_cast<float (*)[GPAD]>(smem + 16384);

        {
            const float4* w4 = reinterpret_cast<const float4*>(W);
            float4* wl4 = reinterpret_cast<float4*>(Wl);
            for (int i = tid; i < D_FEAT * D_FEAT / 4; i += 256) wl4[i] = w4[i];
        }

        const int row0  = blockIdx.x * GR;
        const int nrows = min(GR, N - row0);

        for (int i = tid; i < GR * 16; i += 256) {
            const int r  = i >> 4;
            const int c4 = i & 15;
            if (r < nrows) {
                float4 v = reinterpret_cast<const float4*>(
                               g + (size_t)(row0 + r) * D_FEAT)[c4];
                float* dp = &Gl[r][c4 * 4];
                reinterpret_cast<float2*>(dp)[0] = make_float2(v.x, v.y);
                reinterpret_cast<float2*>(dp)[1] = make_float2(v.z, v.w);
            }
        }
        __syncthreads();

        const int cg = tid & 7;
        const int rg = tid >> 3;
        const int c0 = cg * 8;
        const int r0 = rg * 4;

        float acc[4][8];
#pragma unroll
        for (int i = 0; i < 4; ++i)
#pragma unroll
            for (int j = 0; j < 8; ++j) acc[i][j] = 0.0f;

#pragma unroll 4
        for (int k = 0; k < D_FEAT; ++k) {
            const float4 wa = *reinterpret_cast<const float4*>(&Wl[k * D_FEAT + c0]);
            const float4 wb = *reinterpret_cast<const float4*>(&Wl[k * D_FEAT + c0 + 4]);
            float gv[4];
#pragma unroll
            for (int i = 0; i < 4; ++i) gv[i] = Gl[r0 + i][k];
#pragma unroll
            for (int i = 0; i < 4; ++i) {
                acc[i][0] = fmaf(gv[i], wa.x, acc[i][0]);
                acc[i][1] = fmaf(gv[i], wa.y, acc[i][1]);
                acc[i][2] = fmaf(gv[i], wa.z, acc[i][2]);
                acc[i][3] = fmaf(gv[i], wa.w, acc[i][3]);
                acc[i][4] = fmaf(gv[i], wb.x, acc[i][4]);
                acc[i][5] = fmaf(gv[i], wb.y, acc[i][5]);
                acc[i][6] = fmaf(gv[i], wb.z, acc[i][6]);
                acc[i][7] = fmaf(gv[i], wb.w, acc[i][7]);
            }
        }

#pragma unroll
        for (int i = 0; i < 4; ++i) {
            const int r = r0 + i;
            if (r < nrows) {
                __half2 hb[4];
#pragma unroll
                for (int j = 0; j < 4; ++j)
                    hb[j] = __floats2half2_rn(acc[i][2 * j], acc[i][2 * j + 1]);
                *reinterpret_cast<uint4*>(h16 + (size_t)(row0 + r) * D_FEAT + c0) =
                    *reinterpret_cast<uint4*>(hb);
            }
        }
    } else {
        // ----- bucketA phase -----
        int2* stage  = reinterpret_cast<int2*>(smem);
        int* cnt     = reinterpret_cast<int*>(smem + 20480);
        int* startb  = reinterpret_cast<int*>(smem + 20480 + 1024);
        int* baseb   = reinterpret_cast<int*>(smem + 20480 + 2048);
        int* cnt2    = reinterpret_cast<int*>(smem + 20480 + 3072);
        int* sc      = reinterpret_cast<int*>(smem + 20480 + 4096);

        const int ab = blockIdx.x - gemmGrid;
        const int beg = ab * chunk;
        const int end = min(beg + chunk, E);
        const int n = end - beg;
        if (n <= 0) return;

        cnt[tid] = 0;
        cnt2[tid] = 0;
        __syncthreads();

        for (int i = tid; i < n; i += 256)
            atomicAdd(&cnt[dst[beg + i] >> BSHIFT], 1);
        __syncthreads();

        sc[tid] = (tid < nbuck) ? cnt[tid] : 0;
        __syncthreads();
        for (int off = 1; off < NBUCK_MAX; off <<= 1) {
            int x = (tid >= off) ? sc[tid - off] : 0;
            __syncthreads();
            sc[tid] += x;
            __syncthreads();
        }
        if (tid < nbuck) {
            startb[tid] = sc[tid] - cnt[tid];
            if (cnt[tid] > 0) baseb[tid] = atomicAdd(&bcur[tid], cnt[tid]);
        }
        __syncthreads();

        for (int i = tid; i < n; i += 256) {
            const int d = dst[beg + i];
            const int b = d >> BSHIFT;
            const unsigned pl = pack_edge(src[beg + i], ew[beg + i]);
            const int lp = atomicAdd(&cnt2[b], 1);
            stage[startb[b] + lp] = make_int2(d, (int)pl);
        }
        __syncthreads();

        for (int i = tid; i < n; i += 256) {
            const int2 en = stage[i];
            const int b = en.x >> BSHIFT;
            staged[(size_t)b * BCAP + baseb[b] + (i - startb[b])] = en;
        }
    }
}

// ---------------------------------------------------------------------------
// K2: bucketB — per-bucket per-node hist + scan -> nodeinfo{beg,deg},
// exact-CSR scatter into the bucket's srcw window.
// ---------------------------------------------------------------------------
__global__ __launch_bounds__(256) void bucketB_kernel(
    const int2* __restrict__ staged, const int* __restrict__ bcur,
    int2* __restrict__ nodeinfo, unsigned* __restrict__ srcw,
    int N, int nbuck) {
    __shared__ int cnt[BN];
    __shared__ int cur[BN];
    __shared__ int sc[256];
    const int b = blockIdx.x;
    const int tid = threadIdx.x;
    const int node0 = b << BSHIFT;
    const int beg = b * BCAP;
    const int end = beg + bcur[b];

    cnt[tid] = 0;
    cnt[tid + 256] = 0;
    __syncthreads();

    for (int i = beg + tid; i < end; i += 256) {
        const int2 en = staged[i];
        atomicAdd(&cnt[en.x - node0], 1);
    }
    __syncthreads();

    const int c0 = cnt[2 * tid];
    const int c1 = cnt[2 * tid + 1];
    const int s = c0 + c1;
    sc[tid] = s;
    __syncthreads();
    for (int off = 1; off < 256; off <<= 1) {
        int x = (tid >= off) ? sc[tid - off] : 0;
        __syncthreads();
        sc[tid] += x;
        __syncthreads();
    }
    const int excl = sc[tid] - s + beg;
    {
        const int n0 = node0 + 2 * tid;
        if (n0 < N) {
            nodeinfo[n0] = make_int2(excl, c0);
            cur[2 * tid] = excl;
        }
        if (n0 + 1 < N) {
            nodeinfo[n0 + 1] = make_int2(excl + c0, c1);
            cur[2 * tid + 1] = excl + c0;
        }
    }
    __syncthreads();

    for (int i = beg + tid; i < end; i += 256) {
        const int2 en = staged[i];
        const int pos = atomicAdd(&cur[en.x - node0], 1);
        srcw[pos] = (unsigned)en.y;
    }
}

// ---------------------------------------------------------------------------
// K3: node kernel — NT streams, cached gathers, sign-free tanh.
// ---------------------------------------------------------------------------
__device__ __forceinline__ float fast_tanh(float x) {
    float e = __builtin_amdgcn_exp2f(2.885390082f * x);   // e^{2x}
    float r = __builtin_amdgcn_rcpf(1.0f + e);
    return fmaf(-2.0f, r, 1.0f);                          // (e-1)/(e+1)
}

__global__ void node_kernel(const __half* __restrict__ h16,
                            const float* __restrict__ g,
                            const float* __restrict__ hist,
                            const int2* __restrict__ nodeinfo,
                            const unsigned* __restrict__ srcw,
                            float* __restrict__ out_nodes,
                            float* __restrict__ out_hist, int N) {
    const int lane = threadIdx.x & 63;
    const int wid  = threadIdx.x >> 6;
    const int wpb  = blockDim.x >> 6;
    const int slot = lane >> 4;
    const int fg   = lane & 15;

    for (int n = blockIdx.x * wpb + wid; n < N; n += gridDim.x * wpb) {
        const v2i info = __builtin_nontemporal_load(
            reinterpret_cast<const v2i*>(nodeinfo + n));
        const int beg = info.x;
        const int end = beg + info.y;
        const v4f gd  = nt_load4f(g + (size_t)n * D_FEAT + fg * 4);
        const v4f hv4 = nt_load4f(hist + (size_t)n * D_FEAT + fg * 4);

        float4 acc = make_float4(0.0f, 0.0f, 0.0f, 0.0f);

        for (int base = beg; base < end; base += 64) {
            const int chunk = min(64, end - base);
            const unsigned my_sw =
                __builtin_nontemporal_load(srcw + base + min(lane, chunk - 1));

            for (int g0 = 0; g0 < chunk; g0 += 8) {
                const int ia = g0 + slot;
                const int ib = ia + 4;
                const unsigned pa = (unsigned)__shfl((int)my_sw, ia, 64);
                const unsigned pb = (unsigned)__shfl((int)my_sw, ib, 64);
                const int   sa = pa & 0x1FFFF;
                const float wa = (float)(pa >> 17) * WQ_INV;
                const int   sb = pb & 0x1FFFF;
                const float wb = (float)(pb >> 17) * WQ_INV;
                const bool va = ia < chunk;
                const bool vb = ib < chunk;
                // cached gathers (L2-resident table)
                const uint2 hva = *reinterpret_cast<const uint2*>(
                    h16 + (size_t)sa * D_FEAT + fg * 4);
                const uint2 hvb = *reinterpret_cast<const uint2*>(
                    h16 + (size_t)sb * D_FEAT + fg * 4);

                const float2 a0 = __half22float2(
                    *reinterpret_cast<const __half2*>(&hva.x));
                const float2 a1 = __half22float2(
                    *reinterpret_cast<const __half2*>(&hva.y));
                const float ma = va ? 1.0f : 0.0f;
                acc.x = fmaf(ma, fast_tanh(fmaf(gd.x, wa, a0.x)), acc.x);
                acc.y = fmaf(ma, fast_tanh(fmaf(gd.y, wa, a0.y)), acc.y);
                acc.z = fmaf(ma, fast_tanh(fmaf(gd.z, wa, a1.x)), acc.z);
                acc.w = fmaf(ma, fast_tanh(fmaf(gd.w, wa, a1.y)), acc.w);

                const float2 b0 = __half22float2(
                    *reinterpret_cast<const __half2*>(&hvb.x));
                const float2 b1 = __half22float2(
                    *reinterpret_cast<const __half2*>(&hvb.y));
                const float mb = vb ? 1.0f : 0.0f;
                acc.x = fmaf(mb, fast_tanh(fmaf(gd.x, wb, b0.x)), acc.x);
                acc.y = fmaf(mb, fast_tanh(fmaf(gd.y, wb, b0.y)), acc.y);
                acc.z = fmaf(mb, fast_tanh(fmaf(gd.z, wb, b1.x)), acc.z);
                acc.w = fmaf(mb, fast_tanh(fmaf(gd.w, wb, b1.y)), acc.w);
            }
        }

        acc.x += __shfl_xor(acc.x, 16, 64);
        acc.y += __shfl_xor(acc.y, 16, 64);
        acc.z += __shfl_xor(acc.z, 16, 64);
        acc.w += __shfl_xor(acc.w, 16, 64);
        acc.x += __shfl_xor(acc.x, 32, 64);
        acc.y += __shfl_xor(acc.y, 32, 64);
        acc.z += __shfl_xor(acc.z, 32, 64);
        acc.w += __shfl_xor(acc.w, 32, 64);

        if (lane < 16) {
            v4f on; on.x = acc.x; on.y = acc.y; on.z = acc.z; on.w = acc.w;
            __builtin_nontemporal_store(on, reinterpret_cast<v4f*>(
                out_nodes + (size_t)n * D_FEAT + fg * 4));
            v4f oh;
            oh.x = acc.x + hv4.x;
            oh.y = acc.y + hv4.y;
            oh.z = acc.z + hv4.z;
            oh.w = acc.w + hv4.w;
            __builtin_nontemporal_store(oh, reinterpret_cast<v4f*>(
                out_hist + (size_t)n * D_FEAT + fg * 4));
        }
    }
}

extern "C" void kernel_launch(void* const* d_in, const int* in_sizes, int n_in,
                              void* d_out, int out_size, void* d_ws, size_t ws_size,
                              hipStream_t stream) {
    const float* old_g = (const float*)d_in[0];
    const float* W     = (const float*)d_in[1];
    const float* ew    = (const float*)d_in[2];
    const float* hist  = (const float*)d_in[3];
    const int*   src   = (const int*)d_in[4];
    const int*   dst   = (const int*)d_in[5];

    const int N  = in_sizes[0] / D_FEAT;
    const int E  = in_sizes[4];
    const int ND = N * D_FEAT;
    const int nbuck = (N + BN - 1) >> BSHIFT;   // 196

    float* out_nodes = (float*)d_out;
    float* out_hist  = (float*)d_out + ND;

    // Workspace layout
    char* ws = (char*)d_ws;
    __half* h16     = (__half*)ws;               ws += (size_t)ND * 2;
    int*  bcur      = (int*)ws;                  ws += 256 * 4;
    int2* nodeinfo  = (int2*)ws;                 ws += (size_t)(N + 2) * 8;
    unsigned* srcw  = (unsigned*)ws;             ws += (size_t)nbuck * BCAP * 4;
    int2* staged    = (int2*)ws;                 // nbuck*BCAP entries (8B)

    hipMemsetAsync(bcur, 0, 256 * sizeof(int), stream);

    // K1: fused gemm || bucketA
    {
        const int gemmGrid = (N + GR - 1) / GR;          // 782
        const int chunk = (E + PA_BLOCKS - 1) / PA_BLOCKS;
        gemm_bucketA_kernel<<<gemmGrid + PA_BLOCKS, 256, 0, stream>>>(
            old_g, W, h16, N, src, dst, ew, bcur, staged, E, chunk, nbuck,
            gemmGrid);
    }

    // K2: bucketB — nodeinfo + exact-CSR scatter
    bucketB_kernel<<<nbuck, 256, 0, stream>>>(staged, bcur, nodeinfo,
                                              srcw, N, nbuck);

    // K3: per-node accumulation + fused history
    {
        const int block = 256, wpb = block / 64;
        int grid = (N + wpb - 1) / wpb;
        if (grid > 8192) grid = 8192;
        node_kernel<<<grid, block, 0, stream>>>(h16, old_g, hist, nodeinfo,
                                                srcw, out_nodes, out_hist, N);
    }
}

// Round 29
// 99.706 us; speedup vs baseline: 1.1023x; 1.1023x over previous
//
#include <hip/hip_runtime.h>
#include <hip/hip_bf16.h>
#include <hip/hip_fp16.h>

// N = 100000 nodes, D = 64 features, E = 1250000 edges.
// Inputs: old_g[N,D] f32, W[D,D] f32, edge_weight[E,1] f32,
//         history_db[N,D] f32, src[E] i32, dst[E] i32
// Output: concat(nodes_new[N,D], history_new[N,D]) f32.
//
// Pipeline (3 dispatches + 1 tiny memset)  [R27 measured-best: 99.1 us]:
//  (0) memset bcur[256] = 0;
//  (1) fused gemm||bucketA (mixed-block): GEMM fp16-out || LDS counting-
//      sort into padded bucket regions (dense writes);
//  (2) bucketB: per-bucket LDS per-node hist + scan -> nodeinfo{beg,deg},
//      exact-CSR scatter into the bucket's srcw window;
//  (3) node kernel (R11 form, cached accesses -- R28 showed nt hints
//      regress total by ~10us on gfx950): sign-free tanh, shfl_xor
//      slot-reduce, fused history output.

#define D_FEAT 64
#define WQ_SCALE 32767.0f
#define WQ_INV   (1.0f / 32767.0f)
#define BSHIFT 9          // 512 nodes per bucket
#define BN     (1 << BSHIFT)
#define NBUCK_MAX 256     // ceil(100000/512)=196
#define BCAP   8192       // per-bucket region capacity (mean 6400 + 22 sigma)
#define PA_BLOCKS 512
#define PA_CHUNK_MAX 2560 // >= ceil(E/PA_BLOCKS)=2442

#define GR 128
#define GPAD 66
#define SMEM_BYTES 50176

typedef int v4i __attribute__((ext_vector_type(4)));
typedef int v2i __attribute__((ext_vector_type(2)));

__device__ __forceinline__ unsigned pack_edge(int s, float w) {
    int wq = __float2int_rn(w * WQ_SCALE);
    wq = min(wq, 32767);
    wq = max(wq, 0);
    return (unsigned)s | ((unsigned)wq << 17);
}

// ---------------------------------------------------------------------------
// K1: fused gemm || bucketA.
// ---------------------------------------------------------------------------
__global__ __launch_bounds__(256) void gemm_bucketA_kernel(
    const float* __restrict__ g, const float* __restrict__ W,
    __half* __restrict__ h16, int N,
    const int* __restrict__ src, const int* __restrict__ dst,
    const float* __restrict__ ew, int* __restrict__ bcur,
    int2* __restrict__ staged, int E, int chunk, int nbuck, int gemmGrid) {
    __shared__ __align__(16) char smem[SMEM_BYTES];
    const int tid = threadIdx.x;

    if (blockIdx.x < gemmGrid) {
        // ----- GEMM phase -----
        float* Wl = reinterpret_cast<float*>(smem);
        float (*Gl)[GPAD] = reinterpret_cast<float (*)[GPAD]>(smem + 16384);

        {
            const float4* w4 = reinterpret_cast<const float4*>(W);
            float4* wl4 = reinterpret_cast<float4*>(Wl);
            for (int i = tid; i < D_FEAT * D_FEAT / 4; i += 256) wl4[i] = w4[i];
        }

        const int row0  = blockIdx.x * GR;
        const int nrows = min(GR, N - row0);

        for (int i = tid; i < GR * 16; i += 256) {
            const int r  = i >> 4;
            const int c4 = i & 15;
            if (r < nrows) {
                float4 v = reinterpret_cast<const float4*>(
                               g + (size_t)(row0 + r) * D_FEAT)[c4];
                float* dp = &Gl[r][c4 * 4];
                reinterpret_cast<float2*>(dp)[0] = make_float2(v.x, v.y);
                reinterpret_cast<float2*>(dp)[1] = make_float2(v.z, v.w);
            }
        }
        __syncthreads();

        const int cg = tid & 7;
        const int rg = tid >> 3;
        const int c0 = cg * 8;
        const int r0 = rg * 4;

        float acc[4][8];
#pragma unroll
        for (int i = 0; i < 4; ++i)
#pragma unroll
            for (int j = 0; j < 8; ++j) acc[i][j] = 0.0f;

#pragma unroll 4
        for (int k = 0; k < D_FEAT; ++k) {
            const float4 wa = *reinterpret_cast<const float4*>(&Wl[k * D_FEAT + c0]);
            const float4 wb = *reinterpret_cast<const float4*>(&Wl[k * D_FEAT + c0 + 4]);
            float gv[4];
#pragma unroll
            for (int i = 0; i < 4; ++i) gv[i] = Gl[r0 + i][k];
#pragma unroll
            for (int i = 0; i < 4; ++i) {
                acc[i][0] = fmaf(gv[i], wa.x, acc[i][0]);
                acc[i][1] = fmaf(gv[i], wa.y, acc[i][1]);
                acc[i][2] = fmaf(gv[i], wa.z, acc[i][2]);
                acc[i][3] = fmaf(gv[i], wa.w, acc[i][3]);
                acc[i][4] = fmaf(gv[i], wb.x, acc[i][4]);
                acc[i][5] = fmaf(gv[i], wb.y, acc[i][5]);
                acc[i][6] = fmaf(gv[i], wb.z, acc[i][6]);
                acc[i][7] = fmaf(gv[i], wb.w, acc[i][7]);
            }
        }

#pragma unroll
        for (int i = 0; i < 4; ++i) {
            const int r = r0 + i;
            if (r < nrows) {
                __half2 hb[4];
#pragma unroll
                for (int j = 0; j < 4; ++j)
                    hb[j] = __floats2half2_rn(acc[i][2 * j], acc[i][2 * j + 1]);
                *reinterpret_cast<uint4*>(h16 + (size_t)(row0 + r) * D_FEAT + c0) =
                    *reinterpret_cast<uint4*>(hb);
            }
        }
    } else {
        // ----- bucketA phase -----
        int2* stage  = reinterpret_cast<int2*>(smem);
        int* cnt     = reinterpret_cast<int*>(smem + 20480);
        int* startb  = reinterpret_cast<int*>(smem + 20480 + 1024);
        int* baseb   = reinterpret_cast<int*>(smem + 20480 + 2048);
        int* cnt2    = reinterpret_cast<int*>(smem + 20480 + 3072);
        int* sc      = reinterpret_cast<int*>(smem + 20480 + 4096);

        const int ab = blockIdx.x - gemmGrid;
        const int beg = ab * chunk;
        const int end = min(beg + chunk, E);
        const int n = end - beg;
        if (n <= 0) return;

        cnt[tid] = 0;
        cnt2[tid] = 0;
        __syncthreads();

        for (int i = tid; i < n; i += 256)
            atomicAdd(&cnt[dst[beg + i] >> BSHIFT], 1);
        __syncthreads();

        sc[tid] = (tid < nbuck) ? cnt[tid] : 0;
        __syncthreads();
        for (int off = 1; off < NBUCK_MAX; off <<= 1) {
            int x = (tid >= off) ? sc[tid - off] : 0;
            __syncthreads();
            sc[tid] += x;
            __syncthreads();
        }
        if (tid < nbuck) {
            startb[tid] = sc[tid] - cnt[tid];
            if (cnt[tid] > 0) baseb[tid] = atomicAdd(&bcur[tid], cnt[tid]);
        }
        __syncthreads();

        for (int i = tid; i < n; i += 256) {
            const int d = dst[beg + i];
            const int b = d >> BSHIFT;
            const unsigned pl = pack_edge(src[beg + i], ew[beg + i]);
            const int lp = atomicAdd(&cnt2[b], 1);
            stage[startb[b] + lp] = make_int2(d, (int)pl);
        }
        __syncthreads();

        for (int i = tid; i < n; i += 256) {
            const int2 en = stage[i];
            const int b = en.x >> BSHIFT;
            staged[(size_t)b * BCAP + baseb[b] + (i - startb[b])] = en;
        }
    }
}

// ---------------------------------------------------------------------------
// K2: bucketB — per-bucket per-node hist + scan -> nodeinfo{beg,deg},
// exact-CSR scatter into the bucket's srcw window.
// ---------------------------------------------------------------------------
__global__ __launch_bounds__(256) void bucketB_kernel(
    const int2* __restrict__ staged, const int* __restrict__ bcur,
    int2* __restrict__ nodeinfo, unsigned* __restrict__ srcw,
    int N, int nbuck) {
    __shared__ int cnt[BN];
    __shared__ int cur[BN];
    __shared__ int sc[256];
    const int b = blockIdx.x;
    const int tid = threadIdx.x;
    const int node0 = b << BSHIFT;
    const int beg = b * BCAP;
    const int end = beg + bcur[b];

    cnt[tid] = 0;
    cnt[tid + 256] = 0;
    __syncthreads();

    for (int i = beg + tid; i < end; i += 256) {
        const int2 en = staged[i];
        atomicAdd(&cnt[en.x - node0], 1);
    }
    __syncthreads();

    const int c0 = cnt[2 * tid];
    const int c1 = cnt[2 * tid + 1];
    const int s = c0 + c1;
    sc[tid] = s;
    __syncthreads();
    for (int off = 1; off < 256; off <<= 1) {
        int x = (tid >= off) ? sc[tid - off] : 0;
        __syncthreads();
        sc[tid] += x;
        __syncthreads();
    }
    const int excl = sc[tid] - s + beg;
    {
        const int n0 = node0 + 2 * tid;
        if (n0 < N) {
            nodeinfo[n0] = make_int2(excl, c0);
            cur[2 * tid] = excl;
        }
        if (n0 + 1 < N) {
            nodeinfo[n0 + 1] = make_int2(excl + c0, c1);
            cur[2 * tid + 1] = excl + c0;
        }
    }
    __syncthreads();

    for (int i = beg + tid; i < end; i += 256) {
        const int2 en = staged[i];
        const int pos = atomicAdd(&cur[en.x - node0], 1);
        srcw[pos] = (unsigned)en.y;
    }
}

// ---------------------------------------------------------------------------
// K3: node kernel (R11 form) with sign-free tanh; nodeinfo = {beg, deg}.
// ---------------------------------------------------------------------------
__device__ __forceinline__ float fast_tanh(float x) {
    float e = __builtin_amdgcn_exp2f(2.885390082f * x);   // e^{2x}
    float r = __builtin_amdgcn_rcpf(1.0f + e);
    return fmaf(-2.0f, r, 1.0f);                          // (e-1)/(e+1)
}

__global__ void node_kernel(const __half* __restrict__ h16,
                            const float* __restrict__ g,
                            const float* __restrict__ hist,
                            const int2* __restrict__ nodeinfo,
                            const unsigned* __restrict__ srcw,
                            float* __restrict__ out_nodes,
                            float* __restrict__ out_hist, int N) {
    const int lane = threadIdx.x & 63;
    const int wid  = threadIdx.x >> 6;
    const int wpb  = blockDim.x >> 6;
    const int slot = lane >> 4;
    const int fg   = lane & 15;

    for (int n = blockIdx.x * wpb + wid; n < N; n += gridDim.x * wpb) {
        const int2 info = nodeinfo[n];
        const int beg = info.x;
        const int end = beg + info.y;
        const float4 gd = *reinterpret_cast<const float4*>(
            g + (size_t)n * D_FEAT + fg * 4);
        const float4 hv4 = *reinterpret_cast<const float4*>(
            hist + (size_t)n * D_FEAT + fg * 4);

        float4 acc = make_float4(0.0f, 0.0f, 0.0f, 0.0f);

        for (int base = beg; base < end; base += 64) {
            const int chunk = min(64, end - base);
            const unsigned my_sw = srcw[base + min(lane, chunk - 1)];

            for (int g0 = 0; g0 < chunk; g0 += 8) {
                const int ia = g0 + slot;
                const int ib = ia + 4;
                const unsigned pa = (unsigned)__shfl((int)my_sw, ia, 64);
                const unsigned pb = (unsigned)__shfl((int)my_sw, ib, 64);
                const int   sa = pa & 0x1FFFF;
                const float wa = (float)(pa >> 17) * WQ_INV;
                const int   sb = pb & 0x1FFFF;
                const float wb = (float)(pb >> 17) * WQ_INV;
                const bool va = ia < chunk;
                const bool vb = ib < chunk;
                const uint2 hva = *reinterpret_cast<const uint2*>(
                    h16 + (size_t)sa * D_FEAT + fg * 4);
                const uint2 hvb = *reinterpret_cast<const uint2*>(
                    h16 + (size_t)sb * D_FEAT + fg * 4);

                const float2 a0 = __half22float2(
                    *reinterpret_cast<const __half2*>(&hva.x));
                const float2 a1 = __half22float2(
                    *reinterpret_cast<const __half2*>(&hva.y));
                const float ma = va ? 1.0f : 0.0f;
                acc.x = fmaf(ma, fast_tanh(fmaf(gd.x, wa, a0.x)), acc.x);
                acc.y = fmaf(ma, fast_tanh(fmaf(gd.y, wa, a0.y)), acc.y);
                acc.z = fmaf(ma, fast_tanh(fmaf(gd.z, wa, a1.x)), acc.z);
                acc.w = fmaf(ma, fast_tanh(fmaf(gd.w, wa, a1.y)), acc.w);

                const float2 b0 = __half22float2(
                    *reinterpret_cast<const __half2*>(&hvb.x));
                const float2 b1 = __half22float2(
                    *reinterpret_cast<const __half2*>(&hvb.y));
                const float mb = vb ? 1.0f : 0.0f;
                acc.x = fmaf(mb, fast_tanh(fmaf(gd.x, wb, b0.x)), acc.x);
                acc.y = fmaf(mb, fast_tanh(fmaf(gd.y, wb, b0.y)), acc.y);
                acc.z = fmaf(mb, fast_tanh(fmaf(gd.z, wb, b1.x)), acc.z);
                acc.w = fmaf(mb, fast_tanh(fmaf(gd.w, wb, b1.y)), acc.w);
            }
        }

        acc.x += __shfl_xor(acc.x, 16, 64);
        acc.y += __shfl_xor(acc.y, 16, 64);
        acc.z += __shfl_xor(acc.z, 16, 64);
        acc.w += __shfl_xor(acc.w, 16, 64);
        acc.x += __shfl_xor(acc.x, 32, 64);
        acc.y += __shfl_xor(acc.y, 32, 64);
        acc.z += __shfl_xor(acc.z, 32, 64);
        acc.w += __shfl_xor(acc.w, 32, 64);

        if (lane < 16) {
            reinterpret_cast<float4*>(out_nodes + (size_t)n * D_FEAT)[fg] = acc;
            float4 o;
            o.x = acc.x + hv4.x;
            o.y = acc.y + hv4.y;
            o.z = acc.z + hv4.z;
            o.w = acc.w + hv4.w;
            reinterpret_cast<float4*>(out_hist + (size_t)n * D_FEAT)[fg] = o;
        }
    }
}

extern "C" void kernel_launch(void* const* d_in, const int* in_sizes, int n_in,
                              void* d_out, int out_size, void* d_ws, size_t ws_size,
                              hipStream_t stream) {
    const float* old_g = (const float*)d_in[0];
    const float* W     = (const float*)d_in[1];
    const float* ew    = (const float*)d_in[2];
    const float* hist  = (const float*)d_in[3];
    const int*   src   = (const int*)d_in[4];
    const int*   dst   = (const int*)d_in[5];

    const int N  = in_sizes[0] / D_FEAT;
    const int E  = in_sizes[4];
    const int ND = N * D_FEAT;
    const int nbuck = (N + BN - 1) >> BSHIFT;   // 196

    float* out_nodes = (float*)d_out;
    float* out_hist  = (float*)d_out + ND;

    // Workspace layout
    char* ws = (char*)d_ws;
    __half* h16     = (__half*)ws;               ws += (size_t)ND * 2;
    int*  bcur      = (int*)ws;                  ws += 256 * 4;
    int2* nodeinfo  = (int2*)ws;                 ws += (size_t)(N + 2) * 8;
    unsigned* srcw  = (unsigned*)ws;             ws += (size_t)nbuck * BCAP * 4;
    int2* staged    = (int2*)ws;                 // nbuck*BCAP entries (8B)

    hipMemsetAsync(bcur, 0, 256 * sizeof(int), stream);

    // K1: fused gemm || bucketA
    {
        const int gemmGrid = (N + GR - 1) / GR;          // 782
        const int chunk = (E + PA_BLOCKS - 1) / PA_BLOCKS;
        gemm_bucketA_kernel<<<gemmGrid + PA_BLOCKS, 256, 0, stream>>>(
            old_g, W, h16, N, src, dst, ew, bcur, staged, E, chunk, nbuck,
            gemmGrid);
    }

    // K2: bucketB — nodeinfo + exact-CSR scatter
    bucketB_kernel<<<nbuck, 256, 0, stream>>>(staged, bcur, nodeinfo,
                                              srcw, N, nbuck);

    // K3: per-node accumulation + fused history
    {
        const int block = 256, wpb = block / 64;
        int grid = (N + wpb - 1) / wpb;
        if (grid > 8192) grid = 8192;
        node_kernel<<<grid, block, 0, stream>>>(h16, old_g, hist, nodeinfo,
                                                srcw, out_nodes, out_hist, N);
    }
}